// Round 1
// baseline (2833.282 us; speedup 1.0000x reference)
//
#include <hip/hip_runtime.h>
#include <hip/hip_bf16.h>

typedef __attribute__((ext_vector_type(8))) short bf16x8;
typedef __attribute__((ext_vector_type(4))) float f32x4;

#define N_ROWS 32768
#define K_KEYS 4096
#define DDIM   1024
#define BM 32
#define BK 128
#define NBLK (K_KEYS / BK)   /* 32 */
#define QPITCH 1032          /* 1024 + 8 bf16 pad: row stride 2064B = 516 words == 4 mod 32 */
#define SPITCH 132           /* fp32 pad */
#define PPITCH 136           /* bf16 pad: row stride 272B, 16B aligned */

__device__ __forceinline__ ushort f2bf(float f) {
    __hip_bfloat16 b = __float2bfloat16(f);
    return *(ushort*)&b;
}
__device__ __forceinline__ float bf2f(ushort u) {
    __hip_bfloat16 b = *(__hip_bfloat16*)&u;
    return __bfloat162float(b);
}

// keys fp32 -> hi/lo bf16 split (residual split: hi = rne(f), lo = rne(f - hi))
__global__ void prep_split(const float* __restrict__ src,
                           ushort* __restrict__ hi,
                           ushort* __restrict__ lo) {
    const int total4 = K_KEYS * DDIM / 4;
    int stride = gridDim.x * blockDim.x;
    for (int i = blockIdx.x * blockDim.x + threadIdx.x; i < total4; i += stride) {
        float4 v = ((const float4*)src)[i];
        float f[4] = {v.x, v.y, v.z, v.w};
        ushort h[4], l[4];
#pragma unroll
        for (int j = 0; j < 4; j++) {
            h[j] = f2bf(f[j]);
            l[j] = f2bf(f[j] - bf2f(h[j]));
        }
        ((ushort4*)hi)[i] = make_ushort4(h[0], h[1], h[2], h[3]);
        ((ushort4*)lo)[i] = make_ushort4(l[0], l[1], l[2], l[3]);
    }
}

// values fp32 [K][D] -> vt bf16 [D][K] (transpose so PV B-frags are contiguous)
__global__ void prep_vt(const float* __restrict__ v, ushort* __restrict__ vt) {
    __shared__ float tile[32][33];
    const int tk = blockIdx.x;   // key tile 0..127
    const int td = blockIdx.y;   // d tile   0..31
    const int tx = threadIdx.x;  // 0..31
    const int ty = threadIdx.y;  // 0..7
#pragma unroll
    for (int r = 0; r < 4; r++) {
        int k = tk * 32 + ty + 8 * r;
        tile[ty + 8 * r][tx] = v[(size_t)k * DDIM + td * 32 + tx];
    }
    __syncthreads();
#pragma unroll
    for (int r = 0; r < 4; r++) {
        int d = td * 32 + ty + 8 * r;
        vt[(size_t)d * K_KEYS + tk * 32 + tx] = f2bf(tile[tx][ty + 8 * r]);
    }
}

// fused flash kernel: BM=32 rows/workgroup, 8 waves, BK=128 keys/iter.
// QK^T: wave w owns keys [16w,16w+16), full-D, 3-pass split-bf16.
// PV:   wave w owns output d-chunk [128w,128w+128).
__launch_bounds__(512, 1)
__global__ void attn_main(const float* __restrict__ z,
                          const ushort* __restrict__ kh,
                          const ushort* __restrict__ kl,
                          const ushort* __restrict__ vt,
                          float* __restrict__ out) {
    __shared__ ushort Qh[BM][QPITCH];
    __shared__ ushort Ql[BM][QPITCH];
    __shared__ float  Ssc[BM][SPITCH];
    __shared__ ushort Pt[BM][PPITCH];
    __shared__ float  m_s[BM], l_s[BM], sc_s[BM];

    const int tid  = threadIdx.x;
    const int wave = tid >> 6;
    const int lane = tid & 63;
    const int l16  = lane & 15;
    const int lq   = lane >> 4;       // 0..3
    const int row0 = blockIdx.x * BM;

    // ---- load z rows -> Qh/Ql (split-bf16) ----
#pragma unroll
    for (int j = 0; j < 16; j++) {
        int idx = j * 512 + tid;           // float4 index in [32][256]
        int r   = idx >> 8;
        int c4  = idx & 255;
        float4 v = ((const float4*)(z + (size_t)(row0 + r) * DDIM))[c4];
        float f[4] = {v.x, v.y, v.z, v.w};
        ushort h[4], l[4];
#pragma unroll
        for (int q = 0; q < 4; q++) {
            h[q] = f2bf(f[q]);
            l[q] = f2bf(f[q] - bf2f(h[q]));
        }
        *(ushort4*)&Qh[r][c4 * 4] = make_ushort4(h[0], h[1], h[2], h[3]);
        *(ushort4*)&Ql[r][c4 * 4] = make_ushort4(l[0], l[1], l[2], l[3]);
    }
    if (tid < BM) { m_s[tid] = -1e30f; l_s[tid] = 0.f; }
    __syncthreads();

    f32x4 Oacc[2][8];
#pragma unroll
    for (int mt = 0; mt < 2; mt++)
#pragma unroll
        for (int nt = 0; nt < 8; nt++)
            Oacc[mt][nt] = (f32x4){0.f, 0.f, 0.f, 0.f};

    for (int b = 0; b < NBLK; b++) {
        // ---- QK^T: 3-pass split-bf16, wave handles 16 keys full-D ----
        f32x4 s0 = {0.f, 0.f, 0.f, 0.f};
        f32x4 s1 = {0.f, 0.f, 0.f, 0.f};
        const int kkey = b * BK + wave * 16 + l16;
        const ushort* khp = kh + (size_t)kkey * DDIM + lq * 8;
        const ushort* klp = kl + (size_t)kkey * DDIM + lq * 8;
#pragma unroll 2
        for (int kc = 0; kc < 32; kc++) {
            int d0 = kc * 32 + lq * 8;
            bf16x8 ah0 = *(const bf16x8*)&Qh[l16][d0];
            bf16x8 ah1 = *(const bf16x8*)&Qh[16 + l16][d0];
            bf16x8 al0 = *(const bf16x8*)&Ql[l16][d0];
            bf16x8 al1 = *(const bf16x8*)&Ql[16 + l16][d0];
            bf16x8 bhv = *(const bf16x8*)(khp + kc * 32);
            bf16x8 blv = *(const bf16x8*)(klp + kc * 32);
            s0 = __builtin_amdgcn_mfma_f32_16x16x32_bf16(ah0, bhv, s0, 0, 0, 0);
            s1 = __builtin_amdgcn_mfma_f32_16x16x32_bf16(ah1, bhv, s1, 0, 0, 0);
            s0 = __builtin_amdgcn_mfma_f32_16x16x32_bf16(ah0, blv, s0, 0, 0, 0);
            s1 = __builtin_amdgcn_mfma_f32_16x16x32_bf16(ah1, blv, s1, 0, 0, 0);
            s0 = __builtin_amdgcn_mfma_f32_16x16x32_bf16(al0, bhv, s0, 0, 0, 0);
            s1 = __builtin_amdgcn_mfma_f32_16x16x32_bf16(al1, bhv, s1, 0, 0, 0);
        }
#pragma unroll
        for (int r = 0; r < 4; r++) {
            Ssc[lq * 4 + r][wave * 16 + l16]      = s0[r];
            Ssc[16 + lq * 4 + r][wave * 16 + l16] = s1[r];
        }
        __syncthreads();

        // ---- online softmax: 16 threads per row ----
        {
            int row = tid >> 4;
            int c0  = tid & 15;
            float sv[8];
            float mloc = -1e30f;
#pragma unroll
            for (int j = 0; j < 8; j++) {
                sv[j] = Ssc[row][c0 + 16 * j];
                mloc = fmaxf(mloc, sv[j]);
            }
#pragma unroll
            for (int off = 8; off >= 1; off >>= 1)
                mloc = fmaxf(mloc, __shfl_xor(mloc, off));
            float m_old = m_s[row];
            float m_new = fmaxf(m_old, mloc);
            float psum = 0.f;
#pragma unroll
            for (int j = 0; j < 8; j++) {
                float p = __expf(sv[j] - m_new);
                psum += p;
                Pt[row][c0 + 16 * j] = f2bf(p);
            }
#pragma unroll
            for (int off = 8; off >= 1; off >>= 1)
                psum += __shfl_xor(psum, off);
            if (c0 == 0) {
                float sc = __expf(m_old - m_new);
                l_s[row] = l_s[row] * sc + psum;
                m_s[row] = m_new;
                sc_s[row] = sc;
            }
        }
        __syncthreads();

        // ---- rescale O, then PV for this wave's d-chunk ----
        float sc0[4], sc1[4];
#pragma unroll
        for (int r = 0; r < 4; r++) {
            sc0[r] = sc_s[lq * 4 + r];
            sc1[r] = sc_s[16 + lq * 4 + r];
        }
#pragma unroll
        for (int nt = 0; nt < 8; nt++)
#pragma unroll
            for (int r = 0; r < 4; r++) {
                Oacc[0][nt][r] *= sc0[r];
                Oacc[1][nt][r] *= sc1[r];
            }

        const ushort* vtbase = vt + (size_t)(wave * 128 + l16) * K_KEYS + b * BK + lq * 8;
#pragma unroll
        for (int kc = 0; kc < 4; kc++) {
            bf16x8 pa0 = *(const bf16x8*)&Pt[l16][kc * 32 + lq * 8];
            bf16x8 pa1 = *(const bf16x8*)&Pt[16 + l16][kc * 32 + lq * 8];
#pragma unroll
            for (int nt = 0; nt < 8; nt++) {
                bf16x8 vb = *(const bf16x8*)(vtbase + (size_t)nt * 16 * K_KEYS + kc * 32);
                Oacc[0][nt] = __builtin_amdgcn_mfma_f32_16x16x32_bf16(pa0, vb, Oacc[0][nt], 0, 0, 0);
                Oacc[1][nt] = __builtin_amdgcn_mfma_f32_16x16x32_bf16(pa1, vb, Oacc[1][nt], 0, 0, 0);
            }
        }
        // no barrier needed: next block's post-QK barrier orders PV reads vs Pt writes
    }
    __syncthreads();

    // ---- epilogue: normalize by l and store ----
    float li0[4], li1[4];
#pragma unroll
    for (int r = 0; r < 4; r++) {
        li0[r] = 1.f / l_s[lq * 4 + r];
        li1[r] = 1.f / l_s[16 + lq * 4 + r];
    }
#pragma unroll
    for (int nt = 0; nt < 8; nt++) {
#pragma unroll
        for (int r = 0; r < 4; r++) {
            int col = wave * 128 + nt * 16 + l16;
            int rowA = row0 + lq * 4 + r;
            out[(size_t)rowA * DDIM + col]        = Oacc[0][nt][r] * li0[r];
            out[(size_t)(rowA + 16) * DDIM + col] = Oacc[1][nt][r] * li1[r];
        }
    }
}

extern "C" void kernel_launch(void* const* d_in, const int* in_sizes, int n_in,
                              void* d_out, int out_size, void* d_ws, size_t ws_size,
                              hipStream_t stream) {
    const float* z    = (const float*)d_in[0];
    const float* keys = (const float*)d_in[1];
    const float* vals = (const float*)d_in[2];
    float* outp = (float*)d_out;

    ushort* kh  = (ushort*)d_ws;                       // 8 MB
    ushort* kl  = kh + (size_t)K_KEYS * DDIM;          // 8 MB
    ushort* vtw = kl + (size_t)K_KEYS * DDIM;          // 8 MB

    prep_split<<<2048, 256, 0, stream>>>(keys, kh, kl);
    prep_vt<<<dim3(K_KEYS / 32, DDIM / 32), dim3(32, 8), 0, stream>>>(vals, vtw);
    attn_main<<<N_ROWS / BM, 512, 0, stream>>>(z, kh, kl, vtw, outp);
}